// Round 1
// 185.055 us; speedup vs baseline: 1.0030x; 1.0030x over previous
//
#include <hip/hip_runtime.h>

// Problem constants
#define HB 1024   // NUM_BASIC (GEMM K)
#define HM 8192   // NUM_MIXED (GEMM M)
#define NR 735    // 105*7 actual GEMM N
#define NPAD 768  // padded N (6 tiles of 128)
#define NOUT 57   // output is (HM, 57, 57)

// GEMM tiling
#define BM 64
#define BN 128
#define BK 32

typedef __attribute__((ext_vector_type(8))) _Float16 half8;
typedef __attribute__((ext_vector_type(4))) _Float16 half4v;
typedef __attribute__((ext_vector_type(4))) float floatx4;

// ---------------------------------------------------------------------------
// Kernel 1 (merged preps, independent halves run concurrently in one launch):
//  blocks [0, NPAD):       x2[r][h] = relu(te[h,t]*mat[h,n,m]) as fp16,
//                          padded to 768 rows (zeros), K(h)-contiguous.
//                          r = (t*7+m)*7 + n
//  blocks [NPAD, NPAD+8192): W fp32 -> fp16 (halves GEMM staging bytes)
// ---------------------------------------------------------------------------
__global__ __launch_bounds__(256) void prep_kernel(
    const float* __restrict__ mat, const float* __restrict__ tex,
    const float4* __restrict__ W,
    _Float16* __restrict__ Xh, half4v* __restrict__ Wh) {
  const int blk = blockIdx.x;
  if (blk < NPAD) {
    const int r = blk;
    const int n = r % 7;
    const int tm = r / 7;
    const int m = tm % 7;
    const int t = tm / 7;
#pragma unroll
    for (int i = 0; i < 4; ++i) {
      const int h = i * 256 + threadIdx.x;
      float v = 0.f;
      if (r < NR) {
        const float mv = mat[h * 49 + n * 7 + m];
        const float te = 1.f / (1.f + expf(-tex[h * 15 + t])) + 1.f;
        v = te * mv;
        v = v > 0.f ? v : 0.f;  // relu
      }
      Xh[r * HB + h] = (_Float16)v;
    }
  } else {
    const int idx = (blk - NPAD) * 256 + threadIdx.x;
    const float4 v = W[idx];
    half4v h;
    h.x = (_Float16)v.x;
    h.y = (_Float16)v.y;
    h.z = (_Float16)v.z;
    h.w = (_Float16)v.w;
    Wh[idx] = h;
  }
}

// ---------------------------------------------------------------------------
// Kernel 2: GEMM  Y[j][r] = relu( sum_h Wh[j][h]*Xh[r][h] + b[j] )
// M=8192, N=768(padded), K=1024.
// 64x128 block tile, BK=32, grid 768 blocks = 3 blocks/CU (balanced).
// 4 waves, each a 32x64 sub-tile via 2x4 grid of 16x16x32 f16 MFMAs.
// 2-phase double-buffered pipeline: stage(k+1) issued BEFORE compute(k);
// single vmcnt-drain barrier per K-step (T3 minimum recipe).
// Bijective XCD swizzle: each XCD gets 16 contiguous bm-tiles x all 6 bn
// -> A slice (2MB) + full B (1.5MB) L2-resident per XCD.
// ---------------------------------------------------------------------------
#define STAGE(p, k0)                                                           \
  do {                                                                         \
    const int arow_ = wave * 16 + srow;                                        \
    __builtin_amdgcn_global_load_lds(                                          \
        (const __attribute__((address_space(1))) void*)(                       \
            A + abase + (size_t)arow_ * HB + (k0) + skh),                      \
        (__attribute__((address_space(3))) void*)(&As[p][wave * 512]),         \
        16, 0, 0);                                                             \
    _Pragma("unroll")                                                          \
    for (int it_ = 0; it_ < 2; ++it_) {                                        \
      const int chunk_ = wave * 2 + it_;                                       \
      const int brow_ = chunk_ * 16 + srow;                                    \
      __builtin_amdgcn_global_load_lds(                                        \
          (const __attribute__((address_space(1))) void*)(                     \
              B + bbase + (size_t)brow_ * HB + (k0) + skh),                    \
          (__attribute__((address_space(3))) void*)(&Bs[p][chunk_ * 512]),     \
          16, 0, 0);                                                           \
    }                                                                          \
  } while (0)

__global__ __launch_bounds__(256) void gemm_kernel(
    const _Float16* __restrict__ A,  // Wh [8192][1024]
    const _Float16* __restrict__ B,  // Xh [768][1024]
    const float* __restrict__ bias,  // [8192]
    float* __restrict__ Y) {         // [8192][768]
  __shared__ __align__(16) _Float16 As[2][BM * BK];  // 2 x 4KB
  __shared__ __align__(16) _Float16 Bs[2][BN * BK];  // 2 x 8KB

  const int tid = threadIdx.x;
  const int lane = tid & 63;
  const int wave = tid >> 6;

  // bijective XCD swizzle over 768 blocks (768 = 8 XCD * 96)
  const int bid = blockIdx.x;
  const int wg = (bid & 7) * 96 + (bid >> 3);
  const int bn = wg % 6;
  const int bm = wg / 6;  // 0..127

  const int wm = (wave >> 1) * 32;  // wave sub-tile origin (M)
  const int wn = (wave & 1) * 64;   // wave sub-tile origin (N)

  floatx4 acc[2][4] = {};

  // staging decomposition: 1KB chunks; chunk c covers rows 16c..16c+15;
  // lane l covers LDS bytes c*1024 + l*16 -> row = c*16 + l/4,
  // k-half offset = (l&3)*8.
  const int srow = lane >> 2;
  const int skh = (lane & 3) * 8;
  const size_t abase = (size_t)(bm * BM) * HB;
  const size_t bbase = (size_t)(bn * BN) * HB;

  const int mrow = lane & 15;
  const int quad = lane >> 4;

  STAGE(0, 0);
  __syncthreads();  // drains vmcnt(0): tile 0 visible

  int p = 0;
  for (int k0 = 0; k0 < HB; k0 += BK) {
    if (k0 + BK < HB) STAGE(p ^ 1, k0 + BK);  // prefetch issued pre-compute

    half8 af[2], bf[4];
#pragma unroll
    for (int i = 0; i < 2; ++i)
      af[i] = *(const half8*)(&As[p][(wm + i * 16 + mrow) * BK + quad * 8]);
#pragma unroll
    for (int j = 0; j < 4; ++j)
      bf[j] = *(const half8*)(&Bs[p][(wn + j * 16 + mrow) * BK + quad * 8]);
#pragma unroll
    for (int i = 0; i < 2; ++i)
#pragma unroll
      for (int j = 0; j < 4; ++j)
        acc[i][j] =
            __builtin_amdgcn_mfma_f32_16x16x32_f16(af[i], bf[j], acc[i][j], 0, 0, 0);

    __syncthreads();  // drains this iter's prefetch; all waves done with buf p
    p ^= 1;
  }

  // epilogue: bias + relu, D layout col=lane&15, row=(lane>>4)*4+reg
#pragma unroll
  for (int i = 0; i < 2; ++i) {
#pragma unroll
    for (int j = 0; j < 4; ++j) {
#pragma unroll
      for (int reg = 0; reg < 4; ++reg) {
        const int grow = bm * BM + wm + i * 16 + quad * 4 + reg;
        const int gcol = bn * BN + wn + j * 16 + mrow;
        float v = acc[i][j][reg] + bias[grow];
        v = v > 0.f ? v : 0.f;
        Y[(size_t)grow * NPAD + gcol] = v;
      }
    }
  }
}

// ---------------------------------------------------------------------------
// Kernel 3: per-j epilogue. mixed[r][q] (57x57):
//   r=0: 1 at q%7==0 (9 ones)
//   r>=1 (r-1 = c*7+n): q=0 -> (n==6); q>=1 -> y[j,n,7*(7-c)+q-1]
// where y[j,n,p] = Y[j][p*7+n]. d = rsqrt(max(1,rowsum)); out = d_r*mixed*d_q.
// Rowsum parallelized 4 lanes/row (56 serial adds -> 14 + 2 shfl).
// ---------------------------------------------------------------------------
__global__ __launch_bounds__(256) void epilogue_kernel(
    const float* __restrict__ Y, float* __restrict__ out) {
  const int j = blockIdx.x;
  __shared__ float ly[NR];
  __shared__ float dd[NOUT];

  const float* yj = Y + (size_t)j * NPAD;
  for (int i = threadIdx.x; i < NR; i += 256) ly[i] = yj[i];
  __syncthreads();

  if (threadIdx.x < 4 * NOUT) {
    const int r = threadIdx.x >> 2;
    const int sub = threadIdx.x & 3;
    float s = 0.f;
    if (r == 0) {
      s = (sub == 0) ? 9.f : 0.f;
    } else {
      const int c = (r - 1) / 7;
      const int n = (r - 1) % 7;
      const int base = 7 * (7 - c);          // starts[c]
      if (sub == 0) s = (n == 6) ? 1.f : 0.f;  // mixed[r][0]
#pragma unroll
      for (int p = sub; p < 56; p += 4) s += ly[(base + p) * 7 + n];
    }
    s += __shfl_xor(s, 1);
    s += __shfl_xor(s, 2);
    if (sub == 0) {
      s = s < 1.f ? 1.f : s;  // clip(.,1,None)
      dd[r] = rsqrtf(s);
    }
  }
  __syncthreads();

  float* oj = out + (size_t)j * (NOUT * NOUT);
  for (int i = threadIdx.x; i < NOUT * NOUT; i += 256) {
    const int r = i / NOUT;
    const int q = i % NOUT;
    float v;
    if (r == 0) {
      v = (q % 7 == 0) ? dd[0] * dd[q] : 0.f;
    } else {
      const int c = (r - 1) / 7;
      const int n = (r - 1) % 7;
      if (q == 0)
        v = (n == 6) ? dd[r] * dd[0] : 0.f;
      else
        v = dd[r] * ly[(7 * (7 - c) + q - 1) * 7 + n] * dd[q];
    }
    oj[i] = v;
  }
}

// ---------------------------------------------------------------------------
extern "C" void kernel_launch(void* const* d_in, const int* in_sizes, int n_in,
                              void* d_out, int out_size, void* d_ws, size_t ws_size,
                              hipStream_t stream) {
  const float* mat = (const float*)d_in[0];  // (1024,7,7)
  const float* tex = (const float*)d_in[1];  // (1024,15)
  const float* W = (const float*)d_in[2];    // (8192,1024)
  const float* b = (const float*)d_in[3];    // (8192,)
  float* out = (float*)d_out;                // (8192,57,57)

  char* ws = (char*)d_ws;
  _Float16* Xh = (_Float16*)(ws);                                  // 1.5 MB
  _Float16* Wh = (_Float16*)(ws + (size_t)NPAD * HB * 2);          // 16.8 MB
  float* Y = (float*)(ws + (size_t)NPAD * HB * 2 + (size_t)HM * HB * 2);  // 25.2 MB

  prep_kernel<<<NPAD + HM * HB / 4 / 256, 256, 0, stream>>>(
      mat, tex, (const float4*)W, Xh, (half4v*)Wh);
  gemm_kernel<<<HM / BM * (NPAD / BN), 256, 0, stream>>>(Wh, Xh, b, Y);
  epilogue_kernel<<<HM, 256, 0, stream>>>(Y, out);
}